// Round 1
// baseline (1215.810 us; speedup 1.0000x reference)
//
#include <hip/hip_runtime.h>

#define LNUM 4
#define DMODEL 1024
#define NHEAD 16
#define FDIM 4096
#define BATCH 4
#define SEQ 1024
#define HDIM 64
#define KBAND 8
#define MROWS (BATCH * SEQ)

typedef __attribute__((ext_vector_type(8))) __bf16 bf16x8;
typedef __attribute__((ext_vector_type(4))) float f32x4;

__device__ __forceinline__ unsigned short f2bf(float f) {
  unsigned int u = __builtin_bit_cast(unsigned int, f);
  u = u + 0x7fffu + ((u >> 16) & 1u);
  return (unsigned short)(u >> 16);
}
__device__ __forceinline__ float bf2f(unsigned short h) {
  unsigned int u = ((unsigned int)h) << 16;
  return __builtin_bit_cast(float, u);
}

#define GLOAD16(gp, lp)                                                        \
  __builtin_amdgcn_global_load_lds(                                            \
      (const __attribute__((address_space(1))) void*)(gp),                     \
      (__attribute__((address_space(3))) void*)(lp), 16, 0, 0)

// ---------------- fp32 -> bf16 conversion (vectorized, 4/thread) -----------
__global__ __launch_bounds__(256) void cvt_bf16(const float* __restrict__ in,
                                                unsigned short* __restrict__ out,
                                                long n) {
  long i = ((long)blockIdx.x * 256 + threadIdx.x) * 4;
  if (i + 3 < n) {
    float4 v = *reinterpret_cast<const float4*>(in + i);
    ushort4 o;
    o.x = f2bf(v.x);
    o.y = f2bf(v.y);
    o.z = f2bf(v.z);
    o.w = f2bf(v.w);
    *reinterpret_cast<ushort4*>(out + i) = o;
  }
}

// ---------------- bf16 GEMM, C = A * W^T + bias --------------------------
// A: [M,K] bf16 row-major.  W: [N,K] bf16 row-major (== B^T).
// 128x128 tile, BK=32, 256 threads = 4 waves (2x2), 4x4 16x16x32 MFMA / wave.
// EPI: 0 = bf16 out (+bias), 1 = bf16 out (+bias, exact gelu), 2 = f32 out (+bias)
template <int EPI>
__global__ __launch_bounds__(256) void gemm_bt(const unsigned short* __restrict__ A,
                                               const unsigned short* __restrict__ W,
                                               const float* __restrict__ bias,
                                               void* __restrict__ Cout,
                                               int Ndim, int Kdim) {
  __shared__ unsigned short Asl[128 * 32];
  __shared__ unsigned short Bsl[128 * 32];
  const int tid = threadIdx.x;
  const int wave = tid >> 6;
  const int lane = tid & 63;
  const int bn0 = blockIdx.x * 128;
  const int bm0 = blockIdx.y * 128;

  // staging: tile [128][32] bf16 = 8 KB = 2 instrs x 256 thr x 16 B
  const int e0 = tid * 8;        // element index in tile for chunk 0
  const int r0 = e0 >> 5;        // row 0..63
  const int c0 = e0 & 31;        // k-col

  const unsigned short* gA0 = A + (size_t)(bm0 + r0) * Kdim + c0;
  const unsigned short* gA1 = gA0 + (size_t)64 * Kdim;
  const unsigned short* gB0 = W + (size_t)(bn0 + r0) * Kdim + c0;
  const unsigned short* gB1 = gB0 + (size_t)64 * Kdim;

  // wave-uniform LDS destinations (HW adds lane*16 bytes)
  unsigned short* lA0 = &Asl[wave * 512];
  unsigned short* lA1 = &Asl[2048 + wave * 512];
  unsigned short* lB0 = &Bsl[wave * 512];
  unsigned short* lB1 = &Bsl[2048 + wave * 512];

  f32x4 acc[4][4] = {};

  const int wr = (wave >> 1) * 64;  // wave row origin in tile
  const int wc = (wave & 1) * 64;   // wave col origin in tile
  const int frow = lane & 15;
  const int kof = (lane >> 4) * 8;

  for (int k0 = 0; k0 < Kdim; k0 += 32) {
    GLOAD16(gA0, lA0);
    GLOAD16(gA1, lA1);
    GLOAD16(gB0, lB0);
    GLOAD16(gB1, lB1);
    gA0 += 32; gA1 += 32; gB0 += 32; gB1 += 32;
    __syncthreads();  // drains vmcnt(0): staged data visible
    bf16x8 af[4], bfr[4];
#pragma unroll
    for (int i = 0; i < 4; ++i)
      af[i] = *reinterpret_cast<const bf16x8*>(&Asl[(wr + i * 16 + frow) * 32 + kof]);
#pragma unroll
    for (int j = 0; j < 4; ++j)
      bfr[j] = *reinterpret_cast<const bf16x8*>(&Bsl[(wc + j * 16 + frow) * 32 + kof]);
#pragma unroll
    for (int i = 0; i < 4; ++i)
#pragma unroll
      for (int j = 0; j < 4; ++j)
        acc[i][j] = __builtin_amdgcn_mfma_f32_16x16x32_bf16(af[i], bfr[j], acc[i][j], 0, 0, 0);
    __syncthreads();  // all reads done before next stage overwrites
  }

  // C/D layout (verified m89/m91): col = lane&15, row = (lane>>4)*4 + reg
  const int rr = (lane >> 4) * 4;
  const int cc = lane & 15;
#pragma unroll
  for (int j = 0; j < 4; ++j) {
    const int n = bn0 + wc + j * 16 + cc;
    const float bv = bias[n];
#pragma unroll
    for (int i = 0; i < 4; ++i) {
#pragma unroll
      for (int r = 0; r < 4; ++r) {
        const int m = bm0 + wr + i * 16 + rr + r;
        float v = acc[i][j][r] + bv;
        if (EPI == 1) v = 0.5f * v * (1.0f + erff(v * 0.70710678118654752f));
        if (EPI == 2) {
          reinterpret_cast<float*>(Cout)[(size_t)m * Ndim + n] = v;
        } else {
          reinterpret_cast<unsigned short*>(Cout)[(size_t)m * Ndim + n] = f2bf(v);
        }
      }
    }
  }
}

// ---------------- banded attention: one wave per (b,h,q), lane = d ----------
__global__ __launch_bounds__(256) void attn_band(const unsigned short* __restrict__ qkv,
                                                 unsigned short* __restrict__ outp) {
  const int gw = blockIdx.x * 4 + (threadIdx.x >> 6);
  const int lane = threadIdx.x & 63;
  const int q = gw & (SEQ - 1);
  const int bh = gw >> 10;  // SEQ = 1024
  const int h = bh & (NHEAD - 1);
  const int b = bh >> 4;
  const size_t row0 = (size_t)(b * SEQ + q);
  const size_t stride = 3 * DMODEL;
  const float qv = bf2f(qkv[row0 * stride + h * HDIM + lane]);

  float sc[KBAND];
  float mx = -1e30f;
#pragma unroll
  for (int jj = 0; jj < KBAND; ++jj) {
    const int j = q + jj;
    const int jc = (j < SEQ) ? j : (SEQ - 1);
    float kv = bf2f(qkv[(size_t)(b * SEQ + jc) * stride + DMODEL + h * HDIM + lane]);
    float p = qv * kv;
#pragma unroll
    for (int m = 32; m; m >>= 1) p += __shfl_xor(p, m);
    p *= 0.125f;  // 1/sqrt(64)
    p = (j < SEQ) ? p : -1e30f;
    sc[jj] = p;
    mx = fmaxf(mx, p);
  }
  float denom = 0.f;
  float ov = 0.f;
#pragma unroll
  for (int jj = 0; jj < KBAND; ++jj) {
    const int j = q + jj;
    const int jc = (j < SEQ) ? j : (SEQ - 1);
    float p = __expf(sc[jj] - mx);
    p = (j < SEQ) ? p : 0.f;
    denom += p;
    ov += p * bf2f(qkv[(size_t)(b * SEQ + jc) * stride + 2 * DMODEL + h * HDIM + lane]);
  }
  ov /= denom;
  outp[row0 * DMODEL + h * HDIM + lane] = f2bf(ov);
}

// ---------------- fused residual add + LayerNorm ---------------------------
// y = LN(resid + delta); writes fp32 (next residual / final out) + bf16 (GEMM A)
__global__ __launch_bounds__(256) void add_ln(const float* __restrict__ resid,
                                              const float* __restrict__ delta,
                                              const float* __restrict__ gw,
                                              const float* __restrict__ gb,
                                              float* __restrict__ xf,
                                              unsigned short* __restrict__ xb) {
  const int row = blockIdx.x;
  const int tid = threadIdx.x;
  const float* rp = resid + (size_t)row * DMODEL;
  const float* dp = delta + (size_t)row * DMODEL;
  float v[4];
  float s = 0.f, s2 = 0.f;
#pragma unroll
  for (int i = 0; i < 4; ++i) {
    const int idx = tid + i * 256;
    v[i] = rp[idx] + dp[idx];
    s += v[i];
    s2 += v[i] * v[i];
  }
#pragma unroll
  for (int m = 32; m; m >>= 1) {
    s += __shfl_xor(s, m);
    s2 += __shfl_xor(s2, m);
  }
  __shared__ float wsm[8];
  const int wave = tid >> 6, lane = tid & 63;
  if (lane == 0) {
    wsm[wave] = s;
    wsm[4 + wave] = s2;
  }
  __syncthreads();
  s = wsm[0] + wsm[1] + wsm[2] + wsm[3];
  s2 = wsm[4] + wsm[5] + wsm[6] + wsm[7];
  const float mean = s * (1.f / DMODEL);
  const float var = s2 * (1.f / DMODEL) - mean * mean;
  const float rstd = rsqrtf(var + 1e-5f);
#pragma unroll
  for (int i = 0; i < 4; ++i) {
    const int idx = tid + i * 256;
    const float y = (v[i] - mean) * rstd * gw[idx] + gb[idx];
    xf[(size_t)row * DMODEL + idx] = y;
    xb[(size_t)row * DMODEL + idx] = f2bf(y);
  }
}

extern "C" void kernel_launch(void* const* d_in, const int* in_sizes, int n_in,
                              void* d_out, int out_size, void* d_ws, size_t ws_size,
                              hipStream_t stream) {
  const float* src  = (const float*)d_in[0];
  const float* Wqkv = (const float*)d_in[1];
  const float* bqkv = (const float*)d_in[2];
  const float* Wo   = (const float*)d_in[3];
  const float* bo   = (const float*)d_in[4];
  const float* W1   = (const float*)d_in[5];
  const float* b1   = (const float*)d_in[6];
  const float* W2   = (const float*)d_in[7];
  const float* b2   = (const float*)d_in[8];
  const float* ln1w = (const float*)d_in[9];
  const float* ln1b = (const float*)d_in[10];
  const float* ln2w = (const float*)d_in[11];
  const float* ln2b = (const float*)d_in[12];
  float* out = (float*)d_out;

  // workspace carve-up (total 209,715,200 B)
  char* p = (char*)d_ws;
  unsigned short* wqkv_b = (unsigned short*)p; p += (size_t)LNUM * 3072 * 1024 * 2;
  unsigned short* wo_b   = (unsigned short*)p; p += (size_t)LNUM * 1024 * 1024 * 2;
  unsigned short* w1_b   = (unsigned short*)p; p += (size_t)LNUM * 4096 * 1024 * 2;
  unsigned short* w2_b   = (unsigned short*)p; p += (size_t)LNUM * 1024 * 4096 * 2;
  float*          xf     = (float*)p;          p += (size_t)MROWS * DMODEL * 4;
  unsigned short* xb     = (unsigned short*)p; p += (size_t)MROWS * DMODEL * 2;
  unsigned short* qkvb   = (unsigned short*)p; p += (size_t)MROWS * 3 * DMODEL * 2;
  unsigned short* aob    = (unsigned short*)p; p += (size_t)MROWS * DMODEL * 2;
  float*          tmpf   = (float*)p;          p += (size_t)MROWS * DMODEL * 4;
  unsigned short* hb     = (unsigned short*)p; p += (size_t)MROWS * FDIM * 2;
  if (ws_size < (size_t)(p - (char*)d_ws)) return;  // insufficient scratch

  // fp32 -> bf16 weights + initial activation
  cvt_bf16<<<(long)LNUM * 3072 * 1024 / 1024, 256, 0, stream>>>(Wqkv, wqkv_b, (long)LNUM * 3072 * 1024);
  cvt_bf16<<<(long)LNUM * 1024 * 1024 / 1024, 256, 0, stream>>>(Wo, wo_b, (long)LNUM * 1024 * 1024);
  cvt_bf16<<<(long)LNUM * 4096 * 1024 / 1024, 256, 0, stream>>>(W1, w1_b, (long)LNUM * 4096 * 1024);
  cvt_bf16<<<(long)LNUM * 1024 * 4096 / 1024, 256, 0, stream>>>(W2, w2_b, (long)LNUM * 1024 * 4096);
  cvt_bf16<<<(long)MROWS * DMODEL / 1024, 256, 0, stream>>>(src, xb, (long)MROWS * DMODEL);

  for (int l = 0; l < LNUM; ++l) {
    // QKV projection: [4096,1024] x [3072,1024]^T -> bf16 [4096,3072]
    gemm_bt<0><<<dim3(3072 / 128, MROWS / 128), 256, 0, stream>>>(
        xb, wqkv_b + (size_t)l * 3072 * 1024, bqkv + l * 3072, qkvb, 3072, 1024);
    // banded attention -> bf16 [4096,1024]
    attn_band<<<(BATCH * NHEAD * SEQ) / 4, 256, 0, stream>>>(qkvb, aob);
    // output projection -> f32 [4096,1024]
    gemm_bt<2><<<dim3(1024 / 128, MROWS / 128), 256, 0, stream>>>(
        aob, wo_b + (size_t)l * 1024 * 1024, bo + l * 1024, tmpf, 1024, 1024);
    // x = LN(x + proj)
    add_ln<<<MROWS, 256, 0, stream>>>(l == 0 ? src : xf, tmpf,
                                      ln1w + l * DMODEL, ln1b + l * DMODEL, xf, xb);
    // FFN up + exact gelu -> bf16 [4096,4096]
    gemm_bt<1><<<dim3(FDIM / 128, MROWS / 128), 256, 0, stream>>>(
        xb, w1_b + (size_t)l * 4096 * 1024, b1 + l * FDIM, hb, FDIM, 1024);
    // FFN down -> f32 [4096,1024]
    gemm_bt<2><<<dim3(1024 / 128, MROWS / 128), 256, 0, stream>>>(
        hb, w2_b + (size_t)l * 1024 * 4096, b2 + l * 1024, tmpf, 1024, FDIM);
    // x = LN(x + ffn); last layer writes d_out
    float* dst = (l == LNUM - 1) ? out : xf;
    add_ln<<<MROWS, 256, 0, stream>>>(xf, tmpf,
                                      ln2w + l * DMODEL, ln2b + l * DMODEL, dst, xb);
  }
}

// Round 2
// 1067.125 us; speedup vs baseline: 1.1393x; 1.1393x over previous
//
#include <hip/hip_runtime.h>

#define LNUM 4
#define DMODEL 1024
#define NHEAD 16
#define FDIM 4096
#define BATCH 4
#define SEQ 1024
#define HDIM 64
#define KBAND 8
#define MROWS (BATCH * SEQ)

typedef __attribute__((ext_vector_type(8))) __bf16 bf16x8;
typedef __attribute__((ext_vector_type(4))) float f32x4;

__device__ __forceinline__ unsigned short f2bf(float f) {
  unsigned int u = __builtin_bit_cast(unsigned int, f);
  u = u + 0x7fffu + ((u >> 16) & 1u);
  return (unsigned short)(u >> 16);
}
__device__ __forceinline__ float bf2f(unsigned short h) {
  unsigned int u = ((unsigned int)h) << 16;
  return __builtin_bit_cast(float, u);
}

#define GLOAD16(gp, lp)                                                        \
  __builtin_amdgcn_global_load_lds(                                            \
      (const __attribute__((address_space(1))) void*)(gp),                     \
      (__attribute__((address_space(3))) void*)(lp), 16, 0, 0)

// ---------------- fp32 -> bf16 conversion (vectorized, 4/thread) -----------
__global__ __launch_bounds__(256) void cvt_bf16(const float* __restrict__ in,
                                                unsigned short* __restrict__ out,
                                                long n) {
  long i = ((long)blockIdx.x * 256 + threadIdx.x) * 4;
  if (i + 3 < n) {
    float4 v = *reinterpret_cast<const float4*>(in + i);
    ushort4 o;
    o.x = f2bf(v.x);
    o.y = f2bf(v.y);
    o.z = f2bf(v.z);
    o.w = f2bf(v.w);
    *reinterpret_cast<ushort4*>(out + i) = o;
  }
}

// ---------------- bf16 GEMM, C = A * W^T + bias --------------------------
// A: [M,K] bf16 row-major.  W: [N,K] bf16 row-major (== B^T).
// 128x128 tile, BK=32, 256 threads = 4 waves (2x2), 4x4 16x16x32 MFMA / wave.
// blockIdx.z = K-split index; each z computes K range [z*Ks, (z+1)*Ks).
// EPI: 0 = bf16 out (+bias), 1 = bf16 out (+bias, exact gelu),
//      2 = f32 partial out (bias only on z==0), per-z slab of M*N floats.
template <int EPI>
__global__ __launch_bounds__(256) void gemm_bt(const unsigned short* __restrict__ A,
                                               const unsigned short* __restrict__ W,
                                               const float* __restrict__ bias,
                                               void* __restrict__ Cout,
                                               int Ndim, int Kdim, int Ks) {
  __shared__ unsigned short Asl[128 * 32];
  __shared__ unsigned short Bsl[128 * 32];
  const int tid = threadIdx.x;
  const int wave = tid >> 6;
  const int lane = tid & 63;

  // XCD-aware bijective chunked swizzle (all grids here have nwg % 8 == 0):
  // consecutive original ids round-robin XCDs; remap so each XCD gets a
  // contiguous chunk of tiles -> A/B panel reuse becomes L2-local.
  const int gx = gridDim.x, gy = gridDim.y;
  const int nwg = gx * gy;
  const int lin = blockIdx.x + blockIdx.y * gx;
  const int cpx = nwg >> 3;
  const int swz = (lin & 7) * cpx + (lin >> 3);
  const int bn0 = (swz % gx) * 128;
  const int bm0 = (swz / gx) * 128;

  const int kz0 = blockIdx.z * Ks;

  // staging: tile [128][32] bf16 = 8 KB = 2 instrs x 256 thr x 16 B
  const int e0 = tid * 8;        // element index in tile for chunk 0
  const int r0 = e0 >> 5;        // row 0..63
  const int c0 = e0 & 31;        // k-col

  const unsigned short* gA0 = A + (size_t)(bm0 + r0) * Kdim + kz0 + c0;
  const unsigned short* gA1 = gA0 + (size_t)64 * Kdim;
  const unsigned short* gB0 = W + (size_t)(bn0 + r0) * Kdim + kz0 + c0;
  const unsigned short* gB1 = gB0 + (size_t)64 * Kdim;

  // wave-uniform LDS destinations (HW adds lane*16 bytes)
  unsigned short* lA0 = &Asl[wave * 512];
  unsigned short* lA1 = &Asl[2048 + wave * 512];
  unsigned short* lB0 = &Bsl[wave * 512];
  unsigned short* lB1 = &Bsl[2048 + wave * 512];

  f32x4 acc[4][4] = {};

  const int wr = (wave >> 1) * 64;  // wave row origin in tile
  const int wc = (wave & 1) * 64;   // wave col origin in tile
  const int frow = lane & 15;
  const int kof = (lane >> 4) * 8;

  for (int k0 = 0; k0 < Ks; k0 += 32) {
    GLOAD16(gA0, lA0);
    GLOAD16(gA1, lA1);
    GLOAD16(gB0, lB0);
    GLOAD16(gB1, lB1);
    gA0 += 32; gA1 += 32; gB0 += 32; gB1 += 32;
    __syncthreads();  // drains vmcnt(0): staged data visible
    bf16x8 af[4], bfr[4];
#pragma unroll
    for (int i = 0; i < 4; ++i)
      af[i] = *reinterpret_cast<const bf16x8*>(&Asl[(wr + i * 16 + frow) * 32 + kof]);
#pragma unroll
    for (int j = 0; j < 4; ++j)
      bfr[j] = *reinterpret_cast<const bf16x8*>(&Bsl[(wc + j * 16 + frow) * 32 + kof]);
#pragma unroll
    for (int i = 0; i < 4; ++i)
#pragma unroll
      for (int j = 0; j < 4; ++j)
        acc[i][j] = __builtin_amdgcn_mfma_f32_16x16x32_bf16(af[i], bfr[j], acc[i][j], 0, 0, 0);
    __syncthreads();  // all reads done before next stage overwrites
  }

  // C/D layout (verified m89/m91): col = lane&15, row = (lane>>4)*4 + reg
  const int rr = (lane >> 4) * 4;
  const int cc = lane & 15;
  const bool addb = (EPI != 2) || (blockIdx.z == 0);
  float* outF = reinterpret_cast<float*>(Cout) +
                (size_t)blockIdx.z * ((size_t)gy * 128) * Ndim;
#pragma unroll
  for (int j = 0; j < 4; ++j) {
    const int n = bn0 + wc + j * 16 + cc;
    const float bv = addb ? bias[n] : 0.0f;
#pragma unroll
    for (int i = 0; i < 4; ++i) {
#pragma unroll
      for (int r = 0; r < 4; ++r) {
        const int m = bm0 + wr + i * 16 + rr + r;
        float v = acc[i][j][r] + bv;
        if (EPI == 1) v = 0.5f * v * (1.0f + erff(v * 0.70710678118654752f));
        if (EPI == 2) {
          outF[(size_t)m * Ndim + n] = v;
        } else {
          reinterpret_cast<unsigned short*>(Cout)[(size_t)m * Ndim + n] = f2bf(v);
        }
      }
    }
  }
}

// ---------------- banded attention: one wave per (b,h,q), lane = d ----------
__global__ __launch_bounds__(256) void attn_band(const unsigned short* __restrict__ qkv,
                                                 unsigned short* __restrict__ outp) {
  const int gw = blockIdx.x * 4 + (threadIdx.x >> 6);
  const int lane = threadIdx.x & 63;
  const int q = gw & (SEQ - 1);
  const int bh = gw >> 10;  // SEQ = 1024
  const int h = bh & (NHEAD - 1);
  const int b = bh >> 4;
  const size_t row0 = (size_t)(b * SEQ + q);
  const size_t stride = 3 * DMODEL;
  const float qv = bf2f(qkv[row0 * stride + h * HDIM + lane]);

  float sc[KBAND];
  float mx = -1e30f;
#pragma unroll
  for (int jj = 0; jj < KBAND; ++jj) {
    const int j = q + jj;
    const int jc = (j < SEQ) ? j : (SEQ - 1);
    float kv = bf2f(qkv[(size_t)(b * SEQ + jc) * stride + DMODEL + h * HDIM + lane]);
    float p = qv * kv;
#pragma unroll
    for (int m = 32; m; m >>= 1) p += __shfl_xor(p, m);
    p *= 0.125f;  // 1/sqrt(64)
    p = (j < SEQ) ? p : -1e30f;
    sc[jj] = p;
    mx = fmaxf(mx, p);
  }
  float denom = 0.f;
  float ov = 0.f;
#pragma unroll
  for (int jj = 0; jj < KBAND; ++jj) {
    const int j = q + jj;
    const int jc = (j < SEQ) ? j : (SEQ - 1);
    float p = __expf(sc[jj] - mx);
    p = (j < SEQ) ? p : 0.f;
    denom += p;
    ov += p * bf2f(qkv[(size_t)(b * SEQ + jc) * stride + 2 * DMODEL + h * HDIM + lane]);
  }
  ov /= denom;
  outp[row0 * DMODEL + h * HDIM + lane] = f2bf(ov);
}

// ---------------- fused residual add + 2-way split-K reduce + LayerNorm ----
// y = LN(resid + d0 + d1); writes fp32 (next residual / final out) + bf16
__global__ __launch_bounds__(256) void add_ln(const float* __restrict__ resid,
                                              const float* __restrict__ d0,
                                              const float* __restrict__ d1,
                                              const float* __restrict__ gw,
                                              const float* __restrict__ gb,
                                              float* __restrict__ xf,
                                              unsigned short* __restrict__ xb) {
  const int row = blockIdx.x;
  const int tid = threadIdx.x;
  const float* rp = resid + (size_t)row * DMODEL;
  const float* p0 = d0 + (size_t)row * DMODEL;
  const float* p1 = d1 + (size_t)row * DMODEL;
  float v[4];
  float s = 0.f, s2 = 0.f;
#pragma unroll
  for (int i = 0; i < 4; ++i) {
    const int idx = tid + i * 256;
    v[i] = rp[idx] + p0[idx] + p1[idx];
    s += v[i];
    s2 += v[i] * v[i];
  }
#pragma unroll
  for (int m = 32; m; m >>= 1) {
    s += __shfl_xor(s, m);
    s2 += __shfl_xor(s2, m);
  }
  __shared__ float wsm[8];
  const int wave = tid >> 6, lane = tid & 63;
  if (lane == 0) {
    wsm[wave] = s;
    wsm[4 + wave] = s2;
  }
  __syncthreads();
  s = wsm[0] + wsm[1] + wsm[2] + wsm[3];
  s2 = wsm[4] + wsm[5] + wsm[6] + wsm[7];
  const float mean = s * (1.f / DMODEL);
  const float var = s2 * (1.f / DMODEL) - mean * mean;
  const float rstd = rsqrtf(var + 1e-5f);
#pragma unroll
  for (int i = 0; i < 4; ++i) {
    const int idx = tid + i * 256;
    const float y = (v[i] - mean) * rstd * gw[idx] + gb[idx];
    xf[(size_t)row * DMODEL + idx] = y;
    xb[(size_t)row * DMODEL + idx] = f2bf(y);
  }
}

extern "C" void kernel_launch(void* const* d_in, const int* in_sizes, int n_in,
                              void* d_out, int out_size, void* d_ws, size_t ws_size,
                              hipStream_t stream) {
  const float* src  = (const float*)d_in[0];
  const float* Wqkv = (const float*)d_in[1];
  const float* bqkv = (const float*)d_in[2];
  const float* Wo   = (const float*)d_in[3];
  const float* bo   = (const float*)d_in[4];
  const float* W1   = (const float*)d_in[5];
  const float* b1   = (const float*)d_in[6];
  const float* W2   = (const float*)d_in[7];
  const float* b2   = (const float*)d_in[8];
  const float* ln1w = (const float*)d_in[9];
  const float* ln1b = (const float*)d_in[10];
  const float* ln2w = (const float*)d_in[11];
  const float* ln2b = (const float*)d_in[12];
  float* out = (float*)d_out;

  // workspace carve-up (needs 192,937,984 B of the 209,715,200 provided)
  char* p = (char*)d_ws;
  unsigned short* wqkv_b = (unsigned short*)p; p += (size_t)LNUM * 3072 * 1024 * 2;
  unsigned short* wo_b   = (unsigned short*)p; p += (size_t)LNUM * 1024 * 1024 * 2;
  unsigned short* w1_b   = (unsigned short*)p; p += (size_t)LNUM * 4096 * 1024 * 2;
  unsigned short* w2_b   = (unsigned short*)p; p += (size_t)LNUM * 1024 * 4096 * 2;
  float*          xf     = (float*)p;          p += (size_t)MROWS * DMODEL * 4;
  unsigned short* xb     = (unsigned short*)p; p += (size_t)MROWS * DMODEL * 2;
  // scratch region R, time-multiplexed:
  //   [R +0      .. +25.2MB) qkvb   (bf16, live QKV gemm -> attn)
  //   [R +25.2MB .. +33.6MB) aob    (bf16, live attn -> Wo gemm)
  //   [R +0      .. +33.6MB) hb     (bf16, live W1 gemm -> W2 gemm; aliases qkvb+aob)
  //   [R +33.6MB .. +67.2MB) p0,p1  (f32 split-K partials, live gemm -> add_ln)
  char* R = p;
  unsigned short* qkvb = (unsigned short*)R;
  unsigned short* aob  = (unsigned short*)(R + (size_t)MROWS * 3 * DMODEL * 2);
  unsigned short* hb   = (unsigned short*)R;  // aliases qkvb+aob (33.6 MB)
  float* part          = (float*)(R + (size_t)MROWS * 4096 * 2);
  p = R + (size_t)MROWS * 4096 * 2 + (size_t)2 * MROWS * DMODEL * 4;
  if (ws_size < (size_t)(p - (char*)d_ws)) return;  // insufficient scratch

  // fp32 -> bf16 weights + initial activation
  cvt_bf16<<<(long)LNUM * 3072 * 1024 / 1024, 256, 0, stream>>>(Wqkv, wqkv_b, (long)LNUM * 3072 * 1024);
  cvt_bf16<<<(long)LNUM * 1024 * 1024 / 1024, 256, 0, stream>>>(Wo, wo_b, (long)LNUM * 1024 * 1024);
  cvt_bf16<<<(long)LNUM * 4096 * 1024 / 1024, 256, 0, stream>>>(W1, w1_b, (long)LNUM * 4096 * 1024);
  cvt_bf16<<<(long)LNUM * 1024 * 4096 / 1024, 256, 0, stream>>>(W2, w2_b, (long)LNUM * 1024 * 4096);
  cvt_bf16<<<(long)MROWS * DMODEL / 1024, 256, 0, stream>>>(src, xb, (long)MROWS * DMODEL);

  for (int l = 0; l < LNUM; ++l) {
    // QKV projection: [4096,1024] x [3072,1024]^T -> bf16 [4096,3072]
    gemm_bt<0><<<dim3(3072 / 128, MROWS / 128, 1), 256, 0, stream>>>(
        xb, wqkv_b + (size_t)l * 3072 * 1024, bqkv + l * 3072, qkvb, 3072, 1024, 1024);
    // banded attention -> bf16 [4096,1024]
    attn_band<<<(BATCH * NHEAD * SEQ) / 4, 256, 0, stream>>>(qkvb, aob);
    // output projection, split-K=2 -> f32 partials p0,p1
    gemm_bt<2><<<dim3(1024 / 128, MROWS / 128, 2), 256, 0, stream>>>(
        aob, wo_b + (size_t)l * 1024 * 1024, bo + l * 1024, part, 1024, 1024, 512);
    // x = LN(x + p0 + p1)
    add_ln<<<MROWS, 256, 0, stream>>>(l == 0 ? src : xf, part, part + (size_t)MROWS * DMODEL,
                                      ln1w + l * DMODEL, ln1b + l * DMODEL, xf, xb);
    // FFN up + exact gelu -> bf16 [4096,4096]
    gemm_bt<1><<<dim3(FDIM / 128, MROWS / 128, 1), 256, 0, stream>>>(
        xb, w1_b + (size_t)l * 4096 * 1024, b1 + l * FDIM, hb, FDIM, 1024, 1024);
    // FFN down, split-K=2 (K=4096 -> 2x2048) -> f32 partials
    gemm_bt<2><<<dim3(1024 / 128, MROWS / 128, 2), 256, 0, stream>>>(
        hb, w2_b + (size_t)l * 1024 * 4096, b2 + l * 1024, part, 1024, 4096, 2048);
    // x = LN(x + p0 + p1); last layer writes d_out
    float* dst = (l == LNUM - 1) ? out : xf;
    add_ln<<<MROWS, 256, 0, stream>>>(xf, part, part + (size_t)MROWS * DMODEL,
                                      ln2w + l * DMODEL, ln2b + l * DMODEL, dst, xb);
  }
}